// Round 9
// baseline (137.915 us; speedup 1.0000x reference)
//
#include <hip/hip_runtime.h>

#define B_  2
#define L_  2048
#define D_  1024
#define H_  16
#define HD_ 64

typedef __attribute__((ext_vector_type(8))) short bf16x8;
typedef __attribute__((ext_vector_type(4))) float f32x4;
typedef __attribute__((ext_vector_type(16))) float f32x16;

#define MFMA16(a, b, c) __builtin_amdgcn_mfma_f32_16x16x32_bf16(a, b, c, 0, 0, 0)
#define MFMA32(a, b, c) __builtin_amdgcn_mfma_f32_32x32x16_bf16(a, b, c, 0, 0, 0)

__device__ __forceinline__ unsigned short f2bf(float f) {
    union { float f; unsigned u; } v; v.f = f;
    unsigned r = v.u + 0x7FFFu + ((v.u >> 16) & 1u);
    return (unsigned short)(r >> 16);
}

// pack two f32 -> one dword of 2 bf16 (truncation); elem0 (low16) = a
__device__ __forceinline__ unsigned pkbf(float a, float b) {
    union { float f; unsigned u; } x, y; x.f = a; y.f = b;
    return __builtin_amdgcn_perm(y.u, x.u, 0x07060302u);
}

// ---------------------------------------------------------------------------
// x (fp32) -> bf16
// ---------------------------------------------------------------------------
__global__ __launch_bounds__(256) void convert_bf16(
    const float* __restrict__ in, unsigned short* __restrict__ out, int n4)
{
    for (int i = blockIdx.x * blockDim.x + threadIdx.x; i < n4;
         i += gridDim.x * blockDim.x) {
        float4 v = *(const float4*)(in + (size_t)i * 4);
        ushort4 u;
        u.x = f2bf(v.x); u.y = f2bf(v.y); u.z = f2bf(v.z); u.w = f2bf(v.w);
        *(ushort4*)(out + (size_t)i * 4) = u;
    }
}

// ---------------------------------------------------------------------------
// All three weight transposes in one launch. fp32 [K][N] -> bf16 [N][K].
// ---------------------------------------------------------------------------
__global__ __launch_bounds__(256) void prep_w(
    const float* __restrict__ Wq, const float* __restrict__ Wkv,
    const float* __restrict__ Wo,
    unsigned short* __restrict__ Wqt, unsigned short* __restrict__ Wkvt,
    unsigned short* __restrict__ Wot)
{
    __shared__ float t[32][33];
    const int z = blockIdx.z;
    const float* W;  unsigned short* Wt;  int N, nc;
    if (z == 0)      { W = Wq;  Wt = Wqt;  N = 1024; nc = 0; }
    else if (z == 1) { W = Wo;  Wt = Wot;  N = 1024; nc = 0; }
    else             { W = Wkv; Wt = Wkvt; N = 2048; nc = (z - 2) * 1024; }
    const int tx = threadIdx.x & 31, ty = threadIdx.x >> 5;
    const int n0 = nc + blockIdx.x * 32, k0 = blockIdx.y * 32;
    #pragma unroll
    for (int r = 0; r < 4; ++r)
        t[ty + r * 8][tx] = W[(size_t)(k0 + ty + r * 8) * N + n0 + tx];
    __syncthreads();
    #pragma unroll
    for (int r = 0; r < 4; ++r)
        Wt[(size_t)(n0 + ty + r * 8) * 1024 + k0 + tx] = f2bf(t[tx][ty + r * 8]);
}

// ---------------------------------------------------------------------------
// Fused QKV projection, 256x256 tile, 8-phase pipelined schedule (T2+T3+T4+T5).
// Q (scaled) -> Qb, K -> dense Kb, V -> Vtg transposed. (unchanged)
// ---------------------------------------------------------------------------
__global__ __launch_bounds__(512, 1) void gemm_qkv8(
    const unsigned short* __restrict__ A,    // xb [4096][1024]
    const unsigned short* __restrict__ Bt,   // Wqkvt [3072][1024]
    const float* __restrict__ bq, const float* __restrict__ bkv,
    unsigned short* __restrict__ Qb, unsigned short* __restrict__ Kb,
    unsigned short* __restrict__ Vtg, float qscl)
{
    const int KDIM = 1024, NT = 16;  // K-tiles of 64
    __shared__ __align__(16) unsigned short lds[65536];  // 128 KiB

    const int tid = threadIdx.x;
    const int w = tid >> 6, l = tid & 63, g = l >> 4, ln = l & 15;
    const int wm = (w >> 2) & 1, wn = w & 3;

    const int lin = blockIdx.x;
    const int wg = (lin & 7) * 24 + (lin >> 3);
    const int by = wg / 12, bx = wg % 12;
    const int m0 = by * 256, n0 = bx * 256;

    const int sr8 = w * 8 + (l >> 3);
    const int sc  = (l & 7) ^ ((l >> 3) & 7);
    const unsigned short* Asrc = A  + (size_t)m0 * KDIM + sc * 8;
    const unsigned short* Bsrc = Bt + (size_t)n0 * KDIM + sc * 8;

#define SLOT_A(d, h) (lds + ((d) * 2 + (h)) * 8192)
#define SLOT_B(d, h) (lds + 32768 + ((d) * 2 + (h)) * 8192)

#define STG(slotp, srcp, hh, kt_) do {                                        \
    _Pragma("unroll")                                                         \
    for (int r_ = 0; r_ < 2; ++r_) {                                          \
        const int row_ = (hh) * 128 + r_ * 64 + sr8;                          \
        __builtin_amdgcn_global_load_lds(                                     \
            (const __attribute__((address_space(1))) void*)                   \
                ((srcp) + (size_t)row_ * KDIM + (kt_) * 64),                  \
            (__attribute__((address_space(3))) void*)                         \
                ((slotp) + r_ * 4096 + w * 512 + l * 8),                      \
            16, 0, 0);                                                        \
    }                                                                         \
} while (0)

    f32x4 acc[8][4];
    #pragma unroll
    for (int i = 0; i < 8; ++i)
        #pragma unroll
        for (int j = 0; j < 4; ++j) acc[i][j] = (f32x4){0.f, 0.f, 0.f, 0.f};

    bf16x8 aR[4][2], bB0[2][2], bB1[2][2];

    STG(SLOT_A(0, 0), Asrc, 0, 0);
    STG(SLOT_B(0, 1), Bsrc, 1, 0);
    STG(SLOT_A(0, 1), Asrc, 1, 0);
    STG(SLOT_B(0, 0), Bsrc, 0, 0);
    STG(SLOT_A(1, 0), Asrc, 0, 1);
    STG(SLOT_B(1, 1), Bsrc, 1, 1);

    #pragma unroll 1
    for (int kt = 0; kt < NT; ++kt) {
        const int cur = kt & 1, nxt = cur ^ 1;
        asm volatile("s_waitcnt vmcnt(4)" ::: "memory");
        __builtin_amdgcn_s_barrier();

        // ---- phase A ----
        #pragma unroll
        for (int mi = 0; mi < 4; ++mi)
            #pragma unroll
            for (int kc = 0; kc < 2; ++kc) {
                const int rho = wm * 64 + mi * 16 + ln, c = kc * 4 + g;
                aR[mi][kc] = *(const bf16x8*)
                    (SLOT_A(cur, 0) + rho * 64 + ((c ^ (rho & 7)) * 8));
            }
        #pragma unroll
        for (int ni = 0; ni < 2; ++ni)
            #pragma unroll
            for (int kc = 0; kc < 2; ++kc) {
                const int rho = wn * 32 + ni * 16 + ln, c = kc * 4 + g;
                bB0[ni][kc] = *(const bf16x8*)
                    (SLOT_B(cur, 0) + rho * 64 + ((c ^ (rho & 7)) * 8));
            }
        if (kt + 1 < NT) STG(SLOT_A(nxt, 1), Asrc, 1, kt + 1);
        __builtin_amdgcn_s_barrier();
        asm volatile("s_waitcnt lgkmcnt(0)" ::: "memory");
        __builtin_amdgcn_s_setprio(1);
        #pragma unroll
        for (int mi = 0; mi < 4; ++mi)
            #pragma unroll
            for (int ni = 0; ni < 2; ++ni) {
                acc[mi][ni] = MFMA16(aR[mi][0], bB0[ni][0], acc[mi][ni]);
                acc[mi][ni] = MFMA16(aR[mi][1], bB0[ni][1], acc[mi][ni]);
            }
        __builtin_amdgcn_s_setprio(0);
        __builtin_amdgcn_s_barrier();

        // ---- phase B ----
        #pragma unroll
        for (int ni = 0; ni < 2; ++ni)
            #pragma unroll
            for (int kc = 0; kc < 2; ++kc) {
                const int rho = wn * 32 + ni * 16 + ln, c = kc * 4 + g;
                bB1[ni][kc] = *(const bf16x8*)
                    (SLOT_B(cur, 1) + rho * 64 + ((c ^ (rho & 7)) * 8));
            }
        if (kt + 1 < NT) STG(SLOT_B(nxt, 0), Bsrc, 0, kt + 1);
        __builtin_amdgcn_s_barrier();
        asm volatile("s_waitcnt lgkmcnt(0)" ::: "memory");
        __builtin_amdgcn_s_setprio(1);
        #pragma unroll
        for (int mi = 0; mi < 4; ++mi)
            #pragma unroll
            for (int ni = 0; ni < 2; ++ni) {
                acc[mi][2 + ni] = MFMA16(aR[mi][0], bB1[ni][0], acc[mi][2 + ni]);
                acc[mi][2 + ni] = MFMA16(aR[mi][1], bB1[ni][1], acc[mi][2 + ni]);
            }
        __builtin_amdgcn_s_setprio(0);
        __builtin_amdgcn_s_barrier();

        // ---- phase C ----
        #pragma unroll
        for (int mi = 0; mi < 4; ++mi)
            #pragma unroll
            for (int kc = 0; kc < 2; ++kc) {
                const int rho = wm * 64 + mi * 16 + ln, c = kc * 4 + g;
                aR[mi][kc] = *(const bf16x8*)
                    (SLOT_A(cur, 1) + rho * 64 + ((c ^ (rho & 7)) * 8));
            }
        if (kt + 2 < NT) STG(SLOT_A(cur, 0), Asrc, 0, kt + 2);
        __builtin_amdgcn_s_barrier();
        asm volatile("s_waitcnt lgkmcnt(0)" ::: "memory");
        __builtin_amdgcn_s_setprio(1);
        #pragma unroll
        for (int mi = 0; mi < 4; ++mi)
            #pragma unroll
            for (int ni = 0; ni < 2; ++ni) {
                acc[4 + mi][2 + ni] = MFMA16(aR[mi][0], bB1[ni][0], acc[4 + mi][2 + ni]);
                acc[4 + mi][2 + ni] = MFMA16(aR[mi][1], bB1[ni][1], acc[4 + mi][2 + ni]);
            }
        __builtin_amdgcn_s_setprio(0);
        __builtin_amdgcn_s_barrier();

        // ---- phase D ----
        if (kt + 2 < NT) STG(SLOT_B(cur, 1), Bsrc, 1, kt + 2);
        __builtin_amdgcn_s_barrier();
        __builtin_amdgcn_s_setprio(1);
        #pragma unroll
        for (int mi = 0; mi < 4; ++mi)
            #pragma unroll
            for (int ni = 0; ni < 2; ++ni) {
                acc[4 + mi][ni] = MFMA16(aR[mi][0], bB0[ni][0], acc[4 + mi][ni]);
                acc[4 + mi][ni] = MFMA16(aR[mi][1], bB0[ni][1], acc[4 + mi][ni]);
            }
        __builtin_amdgcn_s_setprio(0);
        __builtin_amdgcn_s_barrier();
    }
#undef STG
#undef SLOT_A
#undef SLOT_B

    const int region = n0 >> 10;  // 0=Q, 1=K, 2=V
    if (region == 2) {
        #pragma unroll
        for (int nh = 0; nh < 2; ++nh)
            #pragma unroll
            for (int ni = 0; ni < 2; ++ni) {
                const int d = n0 - 2048 + nh * 128 + wn * 32 + ni * 16 + ln;
                const float bv = bkv[1024 + d];
                #pragma unroll
                for (int mh = 0; mh < 2; ++mh)
                    #pragma unroll
                    for (int mi = 0; mi < 4; ++mi) {
                        const int tok = m0 + mh * 128 + wm * 64 + mi * 16 + g * 4;
                        const int bb = tok >> 11, t4 = tok & 2047;
                        const f32x4 av = acc[mh * 4 + mi][nh * 2 + ni];
                        ushort4 p4;
                        p4.x = f2bf(av[0] + bv); p4.y = f2bf(av[1] + bv);
                        p4.z = f2bf(av[2] + bv); p4.w = f2bf(av[3] + bv);
                        *(ushort4*)(Vtg + ((size_t)bb * 1024 + d) * 2048 + t4) = p4;
                    }
            }
    } else {
        const int isQ = (region == 0);
        const float osc = isQ ? qscl : 1.f;
        #pragma unroll
        for (int nh = 0; nh < 2; ++nh)
            #pragma unroll
            for (int ni = 0; ni < 2; ++ni) {
                const int col = n0 + nh * 128 + wn * 32 + ni * 16 + ln;
                const float bv = isQ ? bq[col] : bkv[col - 1024];
                const int ck = isQ ? col : col - 1024;
                #pragma unroll
                for (int mh = 0; mh < 2; ++mh)
                    #pragma unroll
                    for (int mi = 0; mi < 4; ++mi) {
                        const int row = m0 + mh * 128 + wm * 64 + mi * 16 + g * 4;
                        const f32x4 av = acc[mh * 4 + mi][nh * 2 + ni];
                        #pragma unroll
                        for (int r = 0; r < 4; ++r) {
                            const float vout = (av[r] + bv) * osc;
                            if (isQ)
                                Qb[(size_t)(row + r) * 1024 + ck] = f2bf(vout);
                            else
                                Kb[(size_t)(row + r) * 1024 + ck] = f2bf(vout);
                        }
                    }
            }
    }
}

// ---------------------------------------------------------------------------
// bf16 MFMA GEMM (out-projection): C[M,N] = A[M,K] @ Bt[N,K]^T + bias (fp32)
// ---------------------------------------------------------------------------
__global__ __launch_bounds__(256) void gemm_bt(
    const unsigned short* __restrict__ A,
    const unsigned short* __restrict__ Bt,
    const float* __restrict__ bias,
    float* __restrict__ Cout, int M, int N, int K)
{
    __shared__ __align__(16) unsigned short As[128 * 32];
    __shared__ __align__(16) unsigned short Bs[128 * 32];
    const int tid = threadIdx.x;
    const int w = tid >> 6, l = tid & 63, g = l >> 4, ln = l & 15;
    const int wm = w >> 1, wn = w & 1;
    const int m0 = blockIdx.y * 128, n0 = blockIdx.x * 128;

    f32x4 acc[4][4];
    #pragma unroll
    for (int i = 0; i < 4; ++i)
        #pragma unroll
        for (int j = 0; j < 4; ++j) acc[i][j] = (f32x4){0.f, 0.f, 0.f, 0.f};

    const char* Ab = (const char*)A;
    const char* Bb = (const char*)Bt;
    const size_t strideK = (size_t)K * 2;

    for (int k0 = 0; k0 < K; k0 += 32) {
        #pragma unroll
        for (int i = 0; i < 2; ++i) {
            const int b = w * 2048 + i * 1024 + l * 16;
            const int row = b >> 6, cb = b & 63;
            __builtin_amdgcn_global_load_lds(
                (const __attribute__((address_space(1))) void*)
                    (Ab + (size_t)(m0 + row) * strideK + (size_t)k0 * 2 + cb),
                (__attribute__((address_space(3))) void*)
                    ((char*)As + w * 2048 + i * 1024),
                16, 0, 0);
            __builtin_amdgcn_global_load_lds(
                (const __attribute__((address_space(1))) void*)
                    (Bb + (size_t)(n0 + row) * strideK + (size_t)k0 * 2 + cb),
                (__attribute__((address_space(3))) void*)
                    ((char*)Bs + w * 2048 + i * 1024),
                16, 0, 0);
        }
        __syncthreads();
        bf16x8 af[4], bfr[4];
        #pragma unroll
        for (int m = 0; m < 4; ++m)
            af[m] = *(const bf16x8*)(As + (wm * 64 + m * 16 + ln) * 32 + g * 8);
        #pragma unroll
        for (int n = 0; n < 4; ++n)
            bfr[n] = *(const bf16x8*)(Bs + (wn * 64 + n * 16 + ln) * 32 + g * 8);
        #pragma unroll
        for (int m = 0; m < 4; ++m)
            #pragma unroll
            for (int n = 0; n < 4; ++n)
                acc[m][n] = MFMA16(af[m], bfr[n], acc[m][n]);
        __syncthreads();
    }

    #pragma unroll
    for (int n = 0; n < 4; ++n) {
        const int col = n0 + wn * 64 + n * 16 + ln;
        const float bv = bias[col];
        #pragma unroll
        for (int m = 0; m < 4; ++m) {
            const int row = m0 + wm * 64 + m * 16 + g * 4;
            #pragma unroll
            for (int r = 0; r < 4; ++r)
                Cout[(size_t)(row + r) * N + col] = acc[m][n][r] + bv;
        }
    }
}

// ---------------------------------------------------------------------------
// bf16 MFMA flash attention v6b: 32x32x16 MFMA, P never touches LDS.
// Swapped QK^T (S^T = mfma(K,Q)): lane's S-col = its own q (col=lane&31);
// lane l and l^32 hold complementary interleaved k-halves of the same q-row
// (C-row = (r&3)+8*(r>>2)+4*(lane>>5)). PV A-fragments rebuilt in-register
// with 16 v_perm packs + 8 v_permlane32_swap per step.
// FIX vs v6: v_permlane32_swap A,B swaps UPPER-of-A with LOWER-of-B, so the
// call is swap(d0,d2)/swap(d1,d3) (was reversed). Verified lane-by-lane:
// X=(q,h0) holds keys {0-3,8-11,..}, Y=(q,h1) {4-7,12-15,..}; after
// swap(d0,d2): d0 = m0 (X:(0,1), Y:(8,9)), d2 = m2 (X:(4,5), Y:(12,13)).
// ---------------------------------------------------------------------------
__global__ __launch_bounds__(256) void attn_mfma(
    const unsigned short* __restrict__ Qb,
    const unsigned short* __restrict__ Kb,
    const unsigned short* __restrict__ Vtg,
    unsigned short* __restrict__ Yb)
{
    __shared__ __align__(16) unsigned short Ks[2][64 * 64];
    __shared__ __align__(16) unsigned short Vs[2][64 * 64];

    const int tid = threadIdx.x;
    const int w = tid >> 6, l = tid & 63;
    const int l31 = l & 31, hi = l >> 5, l7 = l & 7;
    const int dd = blockIdx.x;
    const int bid = (dd & 7) * 64 + (dd >> 3);   // T1 XCD remap (512%8==0)
    const int qc = bid & 15, h = (bid >> 4) & 15, b = bid >> 8;
    const int qrow = b * L_ + qc * 128 + w * 32;

    const int sub = l >> 3;
    const int scc = (l & 7) ^ sub;               // pre-swizzled source chunk
    const unsigned short* ksrc = Kb  + (size_t)(b * L_) * 1024 + h * HD_ + scc * 8;
    const unsigned short* vsrc = Vtg + (size_t)(b * D_ + h * HD_) * 2048 + scc * 8;

#define STAGE(jj, bb) do {                                                    \
    _Pragma("unroll")                                                         \
    for (int i_ = 0; i_ < 2; ++i_) {                                          \
        const int rowK = w * 16 + i_ * 8 + sub;                               \
        __builtin_amdgcn_global_load_lds(                                     \
            (const __attribute__((address_space(1))) void*)                   \
                (ksrc + (size_t)((jj) * 64 + rowK) * 1024),                   \
            (__attribute__((address_space(3))) void*)                         \
                (&Ks[bb][w * 1024 + i_ * 512]), 16, 0, 0);                    \
        __builtin_amdgcn_global_load_lds(                                     \
            (const __attribute__((address_space(1))) void*)                   \
                (vsrc + (size_t)rowK * 2048 + (jj) * 64),                     \
            (__attribute__((address_space(3))) void*)                         \
                (&Vs[bb][w * 1024 + i_ * 512]), 16, 0, 0);                    \
    }                                                                         \
} while (0)

    // Q fragments (B-operand, 32x32x16): col q = l31, k = dh*16 + hi*8 + j.
    // Q pre-scaled by 0.125*log2(e) in the QKV-proj epilogue.
    bf16x8 qa[4];
    #pragma unroll
    for (int dh = 0; dh < 4; ++dh)
        qa[dh] = *(const bf16x8*)
            (Qb + (size_t)(qrow + l31) * D_ + h * HD_ + dh * 16 + hi * 8);

    const f32x16 z16 = {0.f,0.f,0.f,0.f,0.f,0.f,0.f,0.f,
                        0.f,0.f,0.f,0.f,0.f,0.f,0.f,0.f};
    f32x16 o2[2], lacc;
    o2[0] = z16; o2[1] = z16; lacc = z16;

    const short one_s = (short)0x3F80;  // bf16 1.0
    const bf16x8 ones = {one_s, one_s, one_s, one_s, one_s, one_s, one_s, one_s};

#define ATT_BODY(BUF, TNEXT, NBUF, DOSTG) do {                                \
    if (DOSTG) STAGE(TNEXT, NBUF);                                            \
    const unsigned short* Kc = &Ks[BUF][0];                                   \
    const unsigned short* Vc = &Vs[BUF][0];                                   \
    /* K fragments (A-operand): row key = kk*32+l31, k = dh*16+hi*8+j */      \
    bf16x8 kbf[2][4];                                                         \
    _Pragma("unroll")                                                         \
    for (int kk = 0; kk < 2; ++kk)                                            \
        _Pragma("unroll")                                                     \
        for (int dh = 0; dh < 4; ++dh)                                        \
            kbf[kk][dh] = *(const bf16x8*)                                    \
                (Kc + (kk * 32 + l31) * 64 + (((2 * dh + hi) ^ l7) * 8));     \
    f32x16 s2[2];                                                             \
    __builtin_amdgcn_s_setprio(1);                                            \
    _Pragma("unroll")                                                         \
    for (int kk = 0; kk < 2; ++kk) {                                          \
        s2[kk] = MFMA32(kbf[kk][0], qa[0], z16);                              \
        s2[kk] = MFMA32(kbf[kk][1], qa[1], s2[kk]);                           \
        s2[kk] = MFMA32(kbf[kk][2], qa[2], s2[kk]);                           \
        s2[kk] = MFMA32(kbf[kk][3], qa[3], s2[kk]);                           \
    }                                                                         \
    __builtin_amdgcn_s_setprio(0);                                            \
    /* p = exp2(s) in place */                                                \
    _Pragma("unroll")                                                         \
    for (int kk = 0; kk < 2; ++kk)                                            \
        _Pragma("unroll")                                                     \
        for (int r = 0; r < 16; ++r)                                          \
            s2[kk][r] = __builtin_exp2f(s2[kk][r]);                           \
    /* rebuild PV A-fragments: pa[ks] = P[q=l31][k = ks*16 + hi*8 + 0..7] */  \
    bf16x8 pa[4];                                                             \
    _Pragma("unroll")                                                         \
    for (int ks = 0; ks < 4; ++ks) {                                          \
        const int kk = ks >> 1, R = 8 * (ks & 1);                             \
        unsigned d0 = pkbf(s2[kk][R + 0], s2[kk][R + 1]);                     \
        unsigned d1 = pkbf(s2[kk][R + 2], s2[kk][R + 3]);                     \
        unsigned d2 = pkbf(s2[kk][R + 4], s2[kk][R + 5]);                     \
        unsigned d3 = pkbf(s2[kk][R + 6], s2[kk][R + 7]);                     \
        /* upper(d0) <-> lower(d2): d0 -> m0, d2 -> m2 (both halves) */       \
        asm volatile("v_permlane32_swap_b32 %0, %1" : "+v"(d0), "+v"(d2));    \
        asm volatile("v_permlane32_swap_b32 %0, %1" : "+v"(d1), "+v"(d3));    \
        union { unsigned u[4]; bf16x8 v; } pk_;                               \
        pk_.u[0] = d0; pk_.u[1] = d1; pk_.u[2] = d2; pk_.u[3] = d3;           \
        pa[ks] = pk_.v;                                                       \
    }                                                                         \
    /* V fragments (B-operand): col d = dt*32+l31, k = ks*16+hi*8+j */        \
    bf16x8 vbf[2][4];                                                         \
    _Pragma("unroll")                                                         \
    for (int dt = 0; dt < 2; ++dt)                                            \
        _Pragma("unroll")                                                     \
        for (int ks = 0; ks < 4; ++ks)                                        \
            vbf[dt][ks] = *(const bf16x8*)                                    \
                (Vc + (dt * 32 + l31) * 64 + (((2 * ks + hi) ^ l7) * 8));     \
    __builtin_amdgcn_s_setprio(1);                                            \
    _Pragma("unroll")                                                         \
    for (int dt = 0; dt < 2; ++dt)                                            \
        _Pragma("unroll")                                                     \
        for (int ks = 0; ks < 4; ++ks)                                        \
            o2[dt] = MFMA32(pa[ks], vbf[dt][ks], o2[dt]);                     \
    _Pragma("unroll")                                                         \
    for (int ks = 0; ks < 4; ++ks)                                            \
        lacc = MFMA32(pa[ks], ones, lacc);                                    \
    __builtin_amdgcn_s_setprio(0);                                            \
} while (0)

    STAGE(0, 0);
    __syncthreads();

    #pragma unroll 1
    for (int t = 0; t < L_ / 64; t += 2) {
        ATT_BODY(0, t + 1, 1, true);
        __syncthreads();
        ATT_BODY(1, t + 2, 0, (t + 2 < L_ / 64));
        __syncthreads();
    }
#undef ATT_BODY
#undef STAGE

    // epilogue: rows q = qrow + (r&3)+8*(r>>2)+4*hi, cols d = dt*32 + l31
    #pragma unroll
    for (int r = 0; r < 16; ++r) {
        const float inv = 1.f / lacc[r];
        const int row = qrow + (r & 3) + 8 * (r >> 2) + 4 * hi;
        #pragma unroll
        for (int dt = 0; dt < 2; ++dt)
            Yb[(size_t)row * D_ + h * HD_ + dt * 32 + l31] =
                f2bf(o2[dt][r] * inv);
    }
}

// ---------------------------------------------------------------------------
extern "C" void kernel_launch(void* const* d_in, const int* in_sizes, int n_in,
                              void* d_out, int out_size, void* d_ws, size_t ws_size,
                              hipStream_t stream)
{
    const float* x   = (const float*)d_in[0];
    const float* Wq  = (const float*)d_in[1];
    const float* bq  = (const float*)d_in[2];
    const float* Wkv = (const float*)d_in[3];
    const float* bkv = (const float*)d_in[4];
    const float* Wo  = (const float*)d_in[5];
    const float* bo  = (const float*)d_in[6];
    float* out = (float*)d_out;

    const int M = B_ * L_;  // 4096
    unsigned short* ws = (unsigned short*)d_ws;
    unsigned short* xb   = ws;                          // 4M
    unsigned short* Wqt  = xb   + (size_t)M * D_;       // 1M  \ adjacent =
    unsigned short* Wkvt = Wqt  + (size_t)D_ * D_;      // 2M  / Bt[3072][1024]
    unsigned short* Wot  = Wkvt + (size_t)2 * D_ * D_;  // 1M
    unsigned short* Qb   = Wot  + (size_t)D_ * D_;      // 4M
    unsigned short* Kb   = Qb   + (size_t)M * D_;       // 4M
    unsigned short* Vtg  = Kb   + (size_t)M * D_;       // 4M
    unsigned short* Yb   = Vtg  + (size_t)B_ * D_ * L_; // 4M

    const float QSCL = 0.125f * 1.44269504089f;  // 1/sqrt(HD) * log2(e)

    // prep: x -> bf16; all weight transposes in one launch
    convert_bf16<<<2048, 256, 0, stream>>>(x, xb, M * D_ / 4);
    prep_w<<<dim3(32, 32, 4), 256, 0, stream>>>(Wq, Wkv, Wo, Wqt, Wkvt, Wot);

    // fused QKV projection, 256^2 8-phase (192 blocks); V written transposed
    gemm_qkv8<<<dim3(192), 512, 0, stream>>>(xb, Wqt, bq, bkv, Qb, Kb, Vtg, QSCL);

    // flash attention -> Yb bf16 [M][D]
    attn_mfma<<<dim3(B_ * H_ * (L_ / 128)), 256, 0, stream>>>(Qb, Kb, Vtg, Yb);

    // out = Yb@Wo + bo (fp32 out)
    gemm_bt<<<dim3(D_ / 128, M / 128), 256, 0, stream>>>(Yb, Wot, bo, out, M, D_, D_);
}